// Round 1
// baseline (404.146 us; speedup 1.0000x reference)
//
#include <hip/hip_runtime.h>
#include <hip/hip_bf16.h>
#include <stdint.h>

// ---------------------------------------------------------------------------
// CrossAttention: out = concat([rgb, 0.5 * softmax((rgb Wq)(freq Wk)^T/sqrt(D)) @ freq], -1)
// B=8, N=2048, D=E=1024.  All matmuls as bf16 MFMA (16x16x32), fp32 accum.
//
// Memory plan:
//   d_out rows (2048 f32 each, m = b*2048+n in [0,16384)):
//     after gemm<0>:  K bf16 row m in f32 slots [0:512], Q bf16 in [1024:1536]
//     after gemm<2>:  [1024:2048] = 0.5*attn_out (clobbers Q; nothing reads Q then)
//     after copy:     [0:1024]    = rgb           (clobbers K; nothing reads K then)
//   d_ws: S bf16 (64MiB) @0 | freqT bf16 (32MiB) @64Mi | WqT (2MiB) @96Mi | WkT @98Mi
// ---------------------------------------------------------------------------

typedef __attribute__((ext_vector_type(8))) short   bf16x8;
typedef __attribute__((ext_vector_type(4))) float   f32x4;

static __device__ __forceinline__ unsigned short f2b(float f) {
  __hip_bfloat16 h = __float2bfloat16(f);
  return *reinterpret_cast<unsigned short*>(&h);
}
static __device__ __forceinline__ float b2f(unsigned short u) {
  unsigned int x = ((unsigned int)u) << 16;
  return __uint_as_float(x);
}

#define GLOAD_LDS16(g, l) \
  __builtin_amdgcn_global_load_lds( \
      (const __attribute__((address_space(1))) void*)(g), \
      (__attribute__((address_space(3))) void*)(l), 16, 0, 0)

// ---------------------------------------------------------------------------
// Transpose+cast: f32 [R][C] -> bf16 [C][R].  z=0:Wq, z=1:Wk, z=2+b:freq[b]
// ---------------------------------------------------------------------------
__global__ __launch_bounds__(256) void transpose_to_bf16(
    const float* Wq, const float* Wk, const float* freq,
    __hip_bfloat16* WqT, __hip_bfloat16* WkT, __hip_bfloat16* fT) {
  int z = blockIdx.z;
  const float* src; __hip_bfloat16* dst; int R, C;
  if (z == 0)      { src = Wq; dst = WqT; R = 1024; C = 1024; }
  else if (z == 1) { src = Wk; dst = WkT; R = 1024; C = 1024; }
  else { int b = z - 2; src = freq + (size_t)b*2048*1024; dst = fT + (size_t)b*1024*2048; R = 2048; C = 1024; }
  int r0 = blockIdx.x * 32, c0 = blockIdx.y * 32;
  if (r0 >= R) return;
  __shared__ float tile[32][33];
  int tx = threadIdx.x, ty = threadIdx.y;   // 32 x 8
#pragma unroll
  for (int i = 0; i < 4; ++i)
    tile[ty + i*8][tx] = src[(size_t)(r0 + ty + i*8) * C + c0 + tx];
  __syncthreads();
#pragma unroll
  for (int i = 0; i < 4; ++i)
    dst[(size_t)(c0 + ty + i*8) * R + r0 + tx] = __float2bfloat16(tile[tx][ty + i*8]);
}

// ---------------------------------------------------------------------------
// Unified C = A * B^T GEMM, 128x128 tile, BK=32, 4 waves, 16x16x32 bf16 MFMA.
// MODE 0: proj.  z=0: Q=rgb*WqT^T  z=1: K=freq*WkT^T.  A fp32 (cvt at frag read).
//         C -> bf16 packed into d_out (Q at +2048 bf16, K at +0), row stride 4096.
// MODE 1: S = Q*K^T per batch (z=b). A,B bf16 packed in d_out.  C -> bf16 ws S.
// MODE 2: O = P*freqT^T per batch.  C -> f32 0.5*v into out[:,1024+col].
// ---------------------------------------------------------------------------
template<int MODE>
__global__ __launch_bounds__(256) void gemm_bt(
    const void* pA0, const void* pA1, const void* pB0, const void* pB1, void* pC) {
  constexpr int KDIM = (MODE == 2) ? 2048 : 1024;
  const int tid = threadIdx.x;
  const int wid = tid >> 6, lane = tid & 63;
  const int lm = lane & 15, lk = lane >> 4;
  const int wr = wid >> 1, wc = wid & 1;
  const int bz = blockIdx.z;
  const int row0 = blockIdx.x * 128, col0 = blockIdx.y * 128;

  __shared__ __align__(16) unsigned char ldsA[(MODE == 0) ? 16384 : 8192];
  __shared__ __align__(16) unsigned char ldsB[8192];

  const float* Af = nullptr; const __hip_bfloat16* Abf = nullptr;
  const __hip_bfloat16* Bbf = nullptr;
  long astride = 0, bstride = 0;
  if constexpr (MODE == 0) {
    Af = (const float*)(bz ? pA1 : pA0); astride = 1024;
    Bbf = (const __hip_bfloat16*)(bz ? pB1 : pB0); bstride = 1024;
  } else if constexpr (MODE == 1) {
    Abf = (const __hip_bfloat16*)pA0 + (size_t)bz*2048*4096 + 2048; astride = 4096; // Q
    Bbf = (const __hip_bfloat16*)pA0 + (size_t)bz*2048*4096;        bstride = 4096; // K
  } else {
    Abf = (const __hip_bfloat16*)pA0 + (size_t)bz*2048*2048; astride = 2048;        // P
    Bbf = (const __hip_bfloat16*)pB0 + (size_t)bz*1024*2048; bstride = 2048;        // freqT
  }

  f32x4 acc[4][4];
#pragma unroll
  for (int m = 0; m < 4; ++m)
#pragma unroll
    for (int n = 0; n < 4; ++n) acc[m][n] = (f32x4){0.f, 0.f, 0.f, 0.f};

  for (int k0 = 0; k0 < KDIM; k0 += 32) {
    __syncthreads();   // previous compute done before LDS overwrite
    // ---- stage A tile ----
    if constexpr (MODE == 0) {
      // f32 tile [128][32] = 16KB, 1024 16B-chunks
#pragma unroll
      for (int q = 0; q < 4; ++q) {
        int c = q*256 + tid;
        int r = c >> 3, kk = (c & 7) << 2;
        const float* g = Af + (size_t)(row0 + r) * astride + k0 + kk;
        GLOAD_LDS16(g, ldsA + (size_t)(q*256 + (tid & 192)) * 16);
      }
    } else {
      // bf16 tile [128][32] = 8KB, 512 16B-chunks
#pragma unroll
      for (int q = 0; q < 2; ++q) {
        int c = q*256 + tid;
        int r = c >> 2, kk = (c & 3) << 3;
        const __hip_bfloat16* g = Abf + (size_t)(row0 + r) * astride + k0 + kk;
        GLOAD_LDS16(g, ldsA + (size_t)(q*256 + (tid & 192)) * 16);
      }
    }
    // ---- stage B tile (always bf16 [128][32]) ----
#pragma unroll
    for (int q = 0; q < 2; ++q) {
      int c = q*256 + tid;
      int r = c >> 2, kk = (c & 3) << 3;
      const __hip_bfloat16* g = Bbf + (size_t)(col0 + r) * bstride + k0 + kk;
      GLOAD_LDS16(g, ldsB + (size_t)(q*256 + (tid & 192)) * 16);
    }
    __syncthreads();   // drains vmcnt(0): staged data visible

    // ---- fragments + MFMA ----
    bf16x8 bfr[4];
#pragma unroll
    for (int n = 0; n < 4; ++n) {
      int off = ((wc*64 + n*16 + lm) * 32 + lk*8) * 2;
      bfr[n] = *(const bf16x8*)(ldsB + off);
    }
#pragma unroll
    for (int m = 0; m < 4; ++m) {
      bf16x8 afr;
      if constexpr (MODE == 0) {
        int off = ((wr*64 + m*16 + lm) * 32 + lk*8) * 4;
        f32x4 lo = *(const f32x4*)(ldsA + off);
        f32x4 hi = *(const f32x4*)(ldsA + off + 16);
        union { bf16x8 v; unsigned short u[8]; } cv;
#pragma unroll
        for (int j = 0; j < 4; ++j) { cv.u[j] = f2b(lo[j]); cv.u[4+j] = f2b(hi[j]); }
        afr = cv.v;
      } else {
        int off = ((wr*64 + m*16 + lm) * 32 + lk*8) * 2;
        afr = *(const bf16x8*)(ldsA + off);
      }
#pragma unroll
      for (int n = 0; n < 4; ++n)
        acc[m][n] = __builtin_amdgcn_mfma_f32_16x16x32_bf16(afr, bfr[n], acc[m][n], 0, 0, 0);
    }
  }

  // ---- epilogue ----
#pragma unroll
  for (int m = 0; m < 4; ++m)
#pragma unroll
    for (int n = 0; n < 4; ++n)
#pragma unroll
      for (int r = 0; r < 4; ++r) {
        float v = acc[m][n][r];
        int grow = row0 + wr*64 + m*16 + lk*4 + r;
        int gcol = col0 + wc*64 + n*16 + lm;
        if constexpr (MODE == 0) {
          __hip_bfloat16* Cb = (__hip_bfloat16*)pC;
          Cb[(size_t)grow * 4096 + (bz ? 0 : 2048) + gcol] = __float2bfloat16(v);
        } else if constexpr (MODE == 1) {
          __hip_bfloat16* Cb = (__hip_bfloat16*)pC + (size_t)bz*2048*2048;
          Cb[(size_t)grow * 2048 + gcol] = __float2bfloat16(v);
        } else {
          float* Cf = (float*)pC;
          Cf[((size_t)(bz*2048 + grow)) * 2048 + 1024 + gcol] = 0.5f * v;
        }
      }
}

// ---------------------------------------------------------------------------
// Row softmax in place over S (bf16, 2048 per row), scale 1/32 folded in.
// One 256-thread block per row, 8 elems/thread.
// ---------------------------------------------------------------------------
__global__ __launch_bounds__(256) void softmax_rows(__hip_bfloat16* S) {
  const int row = blockIdx.x;
  const int t = threadIdx.x;
  uint32_t* p32 = (uint32_t*)(S + (size_t)row * 2048);
  uint4 raw = ((const uint4*)p32)[t];
  uint32_t w[4] = {raw.x, raw.y, raw.z, raw.w};
  float x[8];
#pragma unroll
  for (int i = 0; i < 4; ++i) {
    x[2*i]   = b2f((unsigned short)(w[i] & 0xffffu)) * 0.03125f;
    x[2*i+1] = b2f((unsigned short)(w[i] >> 16))     * 0.03125f;
  }
  float mx = x[0];
#pragma unroll
  for (int i = 1; i < 8; ++i) mx = fmaxf(mx, x[i]);
  for (int o = 32; o; o >>= 1) mx = fmaxf(mx, __shfl_xor(mx, o));
  __shared__ float redm[4], reds[4];
  int wid = t >> 6;
  if ((t & 63) == 0) redm[wid] = mx;
  __syncthreads();
  mx = fmaxf(fmaxf(redm[0], redm[1]), fmaxf(redm[2], redm[3]));
  float e[8], s = 0.f;
#pragma unroll
  for (int i = 0; i < 8; ++i) { e[i] = __expf(x[i] - mx); s += e[i]; }
  for (int o = 32; o; o >>= 1) s += __shfl_xor(s, o);
  if ((t & 63) == 0) reds[wid] = s;
  __syncthreads();
  s = reds[0] + reds[1] + reds[2] + reds[3];
  float inv = 1.0f / s;
  uint32_t o[4];
#pragma unroll
  for (int i = 0; i < 4; ++i)
    o[i] = (uint32_t)f2b(e[2*i] * inv) | ((uint32_t)f2b(e[2*i+1] * inv) << 16);
  ((uint4*)p32)[t] = make_uint4(o[0], o[1], o[2], o[3]);
}

// ---------------------------------------------------------------------------
// out[m][0:1024] = rgb[m][:]
// ---------------------------------------------------------------------------
__global__ __launch_bounds__(256) void copy_rgb_kernel(const float* rgb, float* out) {
  size_t i = (size_t)blockIdx.x * 256 + threadIdx.x;  // 16384*256 f32x4 chunks
  size_t m = i >> 8;
  int c = (int)(i & 255) << 2;
  f32x4 v = *(const f32x4*)(rgb + m * 1024 + c);
  *(f32x4*)(out + m * 2048 + c) = v;
}

// ---------------------------------------------------------------------------
extern "C" void kernel_launch(void* const* d_in, const int* in_sizes, int n_in,
                              void* d_out, int out_size, void* d_ws, size_t ws_size,
                              hipStream_t stream) {
  const float* rgb  = (const float*)d_in[0];
  const float* freq = (const float*)d_in[1];
  // d_in[2] = ifreq (dead code in reference), d_in[5] = Wv (dead code)
  const float* Wq   = (const float*)d_in[3];
  const float* Wk   = (const float*)d_in[4];
  float* out = (float*)d_out;

  const size_t WS_NEED = (size_t)100 * 1024 * 1024;
  if (ws_size < WS_NEED) return;  // signal: output stays zero -> absmax ~5.4

  char* ws = (char*)d_ws;
  __hip_bfloat16* S   = (__hip_bfloat16*)(ws);                          // 64 MiB
  __hip_bfloat16* fT  = (__hip_bfloat16*)(ws + ((size_t)64 << 20));     // 32 MiB
  __hip_bfloat16* WqT = (__hip_bfloat16*)(ws + ((size_t)96 << 20));     //  2 MiB
  __hip_bfloat16* WkT = (__hip_bfloat16*)(ws + ((size_t)98 << 20));     //  2 MiB

  hipLaunchKernelGGL(transpose_to_bf16, dim3(64, 32, 10), dim3(32, 8), 0, stream,
                     Wq, Wk, freq, WqT, WkT, fT);
  hipLaunchKernelGGL((gemm_bt<0>), dim3(128, 8, 2), dim3(256), 0, stream,
                     (const void*)rgb, (const void*)freq, (const void*)WqT, (const void*)WkT, (void*)out);
  hipLaunchKernelGGL((gemm_bt<1>), dim3(16, 16, 8), dim3(256), 0, stream,
                     (const void*)out, nullptr, nullptr, nullptr, (void*)S);
  hipLaunchKernelGGL(softmax_rows, dim3(16384), dim3(256), 0, stream, S);
  hipLaunchKernelGGL((gemm_bt<2>), dim3(16, 8, 8), dim3(256), 0, stream,
                     (const void*)S, nullptr, (const void*)fT, nullptr, (void*)out);
  hipLaunchKernelGGL(copy_rgb_kernel, dim3(16384), dim3(256), 0, stream, rgb, out);
}

// Round 2
// 402.657 us; speedup vs baseline: 1.0037x; 1.0037x over previous
//
#include <hip/hip_runtime.h>
#include <hip/hip_bf16.h>
#include <stdint.h>

// ---------------------------------------------------------------------------
// CrossAttention: out = concat([rgb, 0.5 * softmax((rgb Wq)(freq Wk)^T/sqrt(D)) @ freq], -1)
// B=8, N=2048, D=E=1024.  All matmuls bf16 MFMA 16x16x32, fp32 accum,
// m97 structure: 128x128 tile, BK=64, global_load_lds width 16, 4 waves.
//
// d_out rows (2048 f32 = 4096 bf16 slots, m = b*2048+n):
//   after gemm<0>:  K bf16 in slots [0:1024], Q bf16 in [2048:3072]
//   after gemm<2>:  f32 [1024:2048] = 0.5*attn_out (clobbers Q; Q dead)
//   after copy:     f32 [0:1024]    = rgb           (clobbers K; K dead)
// d_ws (100 MiB):
//   [0,32Mi)   rB  (rgb bf16)         -- dead after gemm<0>
//   [32,64Mi)  fB  (freq bf16)        -- dead after gemm<0>
//   [0,64Mi)   S   (scores bf16)      -- overlays rB/fB, written by gemm<1>
//   [64,96Mi)  fT  (freq^T bf16)
//   [96,98Mi)  WqT | [98,100Mi) WkT
// ---------------------------------------------------------------------------

typedef __attribute__((ext_vector_type(8))) short   bf16x8;
typedef __attribute__((ext_vector_type(4))) float   f32x4;

static __device__ __forceinline__ unsigned short f2b(float f) {
  __hip_bfloat16 h = __float2bfloat16(f);
  return *reinterpret_cast<unsigned short*>(&h);
}
static __device__ __forceinline__ float b2f(unsigned short u) {
  unsigned int x = ((unsigned int)u) << 16;
  return __uint_as_float(x);
}

#define GLOAD_LDS16(g, l) \
  __builtin_amdgcn_global_load_lds( \
      (const __attribute__((address_space(1))) void*)(g), \
      (__attribute__((address_space(3))) void*)(l), 16, 0, 0)

// ---------------------------------------------------------------------------
// Elementwise cast rgb f32 -> bf16 (8 elems/thread).
// ---------------------------------------------------------------------------
__global__ __launch_bounds__(256) void cast_rgb_bf16(const float* rgb, __hip_bfloat16* rB) {
  size_t i = ((size_t)blockIdx.x * 256 + threadIdx.x) * 8;
  f32x4 a = *(const f32x4*)(rgb + i);
  f32x4 b = *(const f32x4*)(rgb + i + 4);
  union { bf16x8 v; unsigned short u[8]; } cv;
#pragma unroll
  for (int j = 0; j < 4; ++j) { cv.u[j] = f2b(a[j]); cv.u[4 + j] = f2b(b[j]); }
  *(bf16x8*)(rB + i) = cv.v;
}

// ---------------------------------------------------------------------------
// Transpose+cast f32 [R][C] -> bf16 [C][R].  z=0:Wq, z=1:Wk, z=2+b:freq[b].
// freq blocks additionally emit the row-major bf16 cast fB.
// ---------------------------------------------------------------------------
__global__ __launch_bounds__(256) void transpose_to_bf16(
    const float* Wq, const float* Wk, const float* freq,
    __hip_bfloat16* WqT, __hip_bfloat16* WkT, __hip_bfloat16* fT, __hip_bfloat16* fB) {
  int z = blockIdx.z;
  const float* src; __hip_bfloat16* dst; __hip_bfloat16* cpy = nullptr; int R, C;
  if (z == 0)      { src = Wq; dst = WqT; R = 1024; C = 1024; }
  else if (z == 1) { src = Wk; dst = WkT; R = 1024; C = 1024; }
  else {
    int b = z - 2;
    src = freq + (size_t)b*2048*1024; dst = fT + (size_t)b*1024*2048;
    cpy = fB + (size_t)b*2048*1024; R = 2048; C = 1024;
  }
  int r0 = blockIdx.x * 32, c0 = blockIdx.y * 32;
  if (r0 >= R) return;
  __shared__ float tile[32][33];
  int tx = threadIdx.x, ty = threadIdx.y;   // 32 x 8
#pragma unroll
  for (int i = 0; i < 4; ++i) {
    float v = src[(size_t)(r0 + ty + i*8) * C + c0 + tx];
    tile[ty + i*8][tx] = v;
    if (cpy) cpy[(size_t)(r0 + ty + i*8) * C + c0 + tx] = __float2bfloat16(v);
  }
  __syncthreads();
#pragma unroll
  for (int i = 0; i < 4; ++i)
    dst[(size_t)(c0 + ty + i*8) * R + r0 + tx] = __float2bfloat16(tile[tx][ty + i*8]);
}

// ---------------------------------------------------------------------------
// C = A * B^T, 128x128 tile, BK=64, 4 waves (2x2), 4x4 frags 16x16x32 bf16.
// MODE 0: z=0: Q=rB*WqT^T  z=1: K=fB*WkT^T  -> bf16 packed into d_out.
// MODE 1: S = Q*K^T per batch (z=b), A,B packed in d_out -> bf16 S.
// MODE 2: O = P*fT^T per batch -> f32 0.5*v into out[:,1024+col].
// ---------------------------------------------------------------------------
template<int MODE>
__global__ __launch_bounds__(256) void gemm_bt(
    const void* pA0, const void* pA1, const void* pB0, const void* pB1, void* pC) {
  constexpr int KDIM = (MODE == 2) ? 2048 : 1024;
  const int tid = threadIdx.x;
  const int wid = tid >> 6, lane = tid & 63;
  const int lm = lane & 15, lk = lane >> 4;
  const int wr = wid >> 1, wc = wid & 1;
  const int bz = blockIdx.z;
  const int row0 = blockIdx.x * 128, col0 = blockIdx.y * 128;

  __shared__ __align__(16) unsigned char ldsA[16384];   // 128 x 64 bf16
  __shared__ __align__(16) unsigned char ldsB[16384];

  const __hip_bfloat16* A; const __hip_bfloat16* Bp;
  long lda, ldb;
  if constexpr (MODE == 0) {
    A  = (const __hip_bfloat16*)(bz ? pA1 : pA0); lda = 1024;   // rB / fB
    Bp = (const __hip_bfloat16*)(bz ? pB1 : pB0); ldb = 1024;   // WqT / WkT
  } else if constexpr (MODE == 1) {
    A  = (const __hip_bfloat16*)pA0 + (size_t)bz*2048*4096 + 2048; lda = 4096; // Q
    Bp = (const __hip_bfloat16*)pA0 + (size_t)bz*2048*4096;        ldb = 4096; // K
  } else {
    A  = (const __hip_bfloat16*)pA0 + (size_t)bz*2048*2048; lda = 2048;        // P
    Bp = (const __hip_bfloat16*)pB0 + (size_t)bz*1024*2048; ldb = 2048;        // freqT
  }

  f32x4 acc[4][4];
#pragma unroll
  for (int m = 0; m < 4; ++m)
#pragma unroll
    for (int n = 0; n < 4; ++n) acc[m][n] = (f32x4){0.f, 0.f, 0.f, 0.f};

  for (int k0 = 0; k0 < KDIM; k0 += 64) {
    __syncthreads();   // previous compute done before LDS overwrite
    // ---- stage A,B tiles: each 128 rows x 64 bf16 = 16KB = 1024 chunks ----
#pragma unroll
    for (int q = 0; q < 4; ++q) {
      int c = q*256 + tid;
      int r = c >> 3, kk = (c & 7) << 3;     // 8 chunks of 16B per 128B row
      const __hip_bfloat16* gA = A  + (size_t)(row0 + r) * lda + k0 + kk;
      GLOAD_LDS16(gA, ldsA + (size_t)(q*256 + (tid & 192)) * 16);
    }
#pragma unroll
    for (int q = 0; q < 4; ++q) {
      int c = q*256 + tid;
      int r = c >> 3, kk = (c & 7) << 3;
      const __hip_bfloat16* gB = Bp + (size_t)(col0 + r) * ldb + k0 + kk;
      GLOAD_LDS16(gB, ldsB + (size_t)(q*256 + (tid & 192)) * 16);
    }
    __syncthreads();   // drains vmcnt(0): staged data visible

    // ---- fragments + MFMA: 32 MFMA / K-step / wave ----
    bf16x8 bfr[4][2];
#pragma unroll
    for (int n = 0; n < 4; ++n)
#pragma unroll
      for (int s = 0; s < 2; ++s) {
        int off = (wc*64 + n*16 + lm) * 128 + s*64 + lk*16;
        bfr[n][s] = *(const bf16x8*)(ldsB + off);
      }
#pragma unroll
    for (int m = 0; m < 4; ++m) {
      bf16x8 afr[2];
#pragma unroll
      for (int s = 0; s < 2; ++s) {
        int off = (wr*64 + m*16 + lm) * 128 + s*64 + lk*16;
        afr[s] = *(const bf16x8*)(ldsA + off);
      }
#pragma unroll
      for (int n = 0; n < 4; ++n)
#pragma unroll
        for (int s = 0; s < 2; ++s)
          acc[m][n] = __builtin_amdgcn_mfma_f32_16x16x32_bf16(afr[s], bfr[n][s], acc[m][n], 0, 0, 0);
    }
  }

  // ---- epilogue ----
#pragma unroll
  for (int m = 0; m < 4; ++m)
#pragma unroll
    for (int n = 0; n < 4; ++n)
#pragma unroll
      for (int r = 0; r < 4; ++r) {
        float v = acc[m][n][r];
        int grow = row0 + wr*64 + m*16 + lk*4 + r;
        int gcol = col0 + wc*64 + n*16 + lm;
        if constexpr (MODE == 0) {
          __hip_bfloat16* Cb = (__hip_bfloat16*)pC;
          Cb[(size_t)grow * 4096 + (bz ? 0 : 2048) + gcol] = __float2bfloat16(v);
        } else if constexpr (MODE == 1) {
          __hip_bfloat16* Cb = (__hip_bfloat16*)pC + (size_t)bz*2048*2048;
          Cb[(size_t)grow * 2048 + gcol] = __float2bfloat16(v);
        } else {
          float* Cf = (float*)pC;
          Cf[((size_t)(bz*2048 + grow)) * 2048 + 1024 + gcol] = 0.5f * v;
        }
      }
}

// ---------------------------------------------------------------------------
// Row softmax in place over S (bf16, 2048 per row), scale 1/32 folded in.
// ---------------------------------------------------------------------------
__global__ __launch_bounds__(256) void softmax_rows(__hip_bfloat16* S) {
  const int row = blockIdx.x;
  const int t = threadIdx.x;
  uint32_t* p32 = (uint32_t*)(S + (size_t)row * 2048);
  uint4 raw = ((const uint4*)p32)[t];
  uint32_t w[4] = {raw.x, raw.y, raw.z, raw.w};
  float x[8];
#pragma unroll
  for (int i = 0; i < 4; ++i) {
    x[2*i]   = b2f((unsigned short)(w[i] & 0xffffu)) * 0.03125f;
    x[2*i+1] = b2f((unsigned short)(w[i] >> 16))     * 0.03125f;
  }
  float mx = x[0];
#pragma unroll
  for (int i = 1; i < 8; ++i) mx = fmaxf(mx, x[i]);
  for (int o = 32; o; o >>= 1) mx = fmaxf(mx, __shfl_xor(mx, o));
  __shared__ float redm[4], reds[4];
  int wid = t >> 6;
  if ((t & 63) == 0) redm[wid] = mx;
  __syncthreads();
  mx = fmaxf(fmaxf(redm[0], redm[1]), fmaxf(redm[2], redm[3]));
  float e[8], s = 0.f;
#pragma unroll
  for (int i = 0; i < 8; ++i) { e[i] = __expf(x[i] - mx); s += e[i]; }
  for (int o = 32; o; o >>= 1) s += __shfl_xor(s, o);
  if ((t & 63) == 0) reds[wid] = s;
  __syncthreads();
  s = reds[0] + reds[1] + reds[2] + reds[3];
  float inv = 1.0f / s;
  uint32_t o[4];
#pragma unroll
  for (int i = 0; i < 4; ++i)
    o[i] = (uint32_t)f2b(e[2*i] * inv) | ((uint32_t)f2b(e[2*i+1] * inv) << 16);
  ((uint4*)p32)[t] = make_uint4(o[0], o[1], o[2], o[3]);
}

// ---------------------------------------------------------------------------
// out[m][0:1024] = rgb[m][:]
// ---------------------------------------------------------------------------
__global__ __launch_bounds__(256) void copy_rgb_kernel(const float* rgb, float* out) {
  size_t i = (size_t)blockIdx.x * 256 + threadIdx.x;
  size_t m = i >> 8;
  int c = (int)(i & 255) << 2;
  f32x4 v = *(const f32x4*)(rgb + m * 1024 + c);
  *(f32x4*)(out + m * 2048 + c) = v;
}

// ---------------------------------------------------------------------------
extern "C" void kernel_launch(void* const* d_in, const int* in_sizes, int n_in,
                              void* d_out, int out_size, void* d_ws, size_t ws_size,
                              hipStream_t stream) {
  const float* rgb  = (const float*)d_in[0];
  const float* freq = (const float*)d_in[1];
  // d_in[2] = ifreq (dead), d_in[5] = Wv (dead)
  const float* Wq   = (const float*)d_in[3];
  const float* Wk   = (const float*)d_in[4];
  float* out = (float*)d_out;

  const size_t WS_NEED = (size_t)100 * 1024 * 1024;
  if (ws_size < WS_NEED) return;

  char* ws = (char*)d_ws;
  __hip_bfloat16* rB  = (__hip_bfloat16*)(ws);                          // 32 MiB
  __hip_bfloat16* fB  = (__hip_bfloat16*)(ws + ((size_t)32 << 20));     // 32 MiB
  __hip_bfloat16* S   = (__hip_bfloat16*)(ws);                          // 64 MiB (overlays rB/fB)
  __hip_bfloat16* fT  = (__hip_bfloat16*)(ws + ((size_t)64 << 20));     // 32 MiB
  __hip_bfloat16* WqT = (__hip_bfloat16*)(ws + ((size_t)96 << 20));     //  2 MiB
  __hip_bfloat16* WkT = (__hip_bfloat16*)(ws + ((size_t)98 << 20));     //  2 MiB

  hipLaunchKernelGGL(cast_rgb_bf16, dim3(8192), dim3(256), 0, stream, rgb, rB);
  hipLaunchKernelGGL(transpose_to_bf16, dim3(64, 32, 10), dim3(32, 8), 0, stream,
                     Wq, Wk, freq, WqT, WkT, fT, fB);
  hipLaunchKernelGGL((gemm_bt<0>), dim3(128, 8, 2), dim3(256), 0, stream,
                     (const void*)rB, (const void*)fB, (const void*)WqT, (const void*)WkT, (void*)out);
  hipLaunchKernelGGL((gemm_bt<1>), dim3(16, 16, 8), dim3(256), 0, stream,
                     (const void*)out, nullptr, nullptr, nullptr, (void*)S);
  hipLaunchKernelGGL(softmax_rows, dim3(16384), dim3(256), 0, stream, S);
  hipLaunchKernelGGL((gemm_bt<2>), dim3(16, 8, 8), dim3(256), 0, stream,
                     (const void*)S, nullptr, (const void*)fT, nullptr, (void*)out);
  hipLaunchKernelGGL(copy_rgb_kernel, dim3(16384), dim3(256), 0, stream, rgb, out);
}

// Round 3
// 311.805 us; speedup vs baseline: 1.2961x; 1.2914x over previous
//
#include <hip/hip_runtime.h>
#include <hip/hip_bf16.h>
#include <stdint.h>

// ---------------------------------------------------------------------------
// CrossAttention: out = concat([rgb, 0.5 * softmax((rgb Wq)(freq Wk)^T/sqrt(D)) @ freq], -1)
// B=8, N=2048, D=E=1024.
// GEMMs use the 256^2 8-phase template (m201): BM=BN=256, BK=64, 8 waves,
// 128KiB LDS double-buffer (per K-tile), st_16x32 XOR swizzle (T2), counted
// vmcnt across barriers (T3+T4), setprio around MFMA clusters (T5), bijective
// XCD blockIdx swizzle (T1).
//
// d_out rows (2048 f32 = 4096 bf16 slots, m = b*2048+n):
//   after gemm<0>:  K bf16 in slots [0:1024], Q bf16 in [2048:3072]
//   after gemm<2>:  f32 [1024:2048] = 0.5*attn_out (clobbers Q; Q dead)
//   after copy:     f32 [0:1024]    = rgb           (clobbers K; K dead)
// d_ws (100 MiB):
//   [0,32Mi) rB | [32,64Mi) fB   -- dead after gemm<0>
//   [0,64Mi) S (overlays rB/fB)  -- written by gemm<1>
//   [64,96Mi) fT | [96,98Mi) WqT | [98,100Mi) WkT
// ---------------------------------------------------------------------------

typedef __attribute__((ext_vector_type(8))) short   bf16x8;
typedef __attribute__((ext_vector_type(4))) float   f32x4;

static __device__ __forceinline__ unsigned short f2b(float f) {
  __hip_bfloat16 h = __float2bfloat16(f);
  return *reinterpret_cast<unsigned short*>(&h);
}
static __device__ __forceinline__ float b2f(unsigned short u) {
  unsigned int x = ((unsigned int)u) << 16;
  return __uint_as_float(x);
}

#define GLOAD_LDS16(g, l) \
  __builtin_amdgcn_global_load_lds( \
      (const __attribute__((address_space(1))) void*)(g), \
      (__attribute__((address_space(3))) void*)(l), 16, 0, 0)

// ---------------------------------------------------------------------------
// Elementwise cast rgb f32 -> bf16.
// ---------------------------------------------------------------------------
__global__ __launch_bounds__(256) void cast_rgb_bf16(const float* rgb, __hip_bfloat16* rB) {
  size_t i = ((size_t)blockIdx.x * 256 + threadIdx.x) * 8;
  f32x4 a = *(const f32x4*)(rgb + i);
  f32x4 b = *(const f32x4*)(rgb + i + 4);
  union { bf16x8 v; unsigned short u[8]; } cv;
#pragma unroll
  for (int j = 0; j < 4; ++j) { cv.u[j] = f2b(a[j]); cv.u[4 + j] = f2b(b[j]); }
  *(bf16x8*)(rB + i) = cv.v;
}

// ---------------------------------------------------------------------------
// Transpose+cast f32 [R][C] -> bf16 [C][R].  z=0:Wq, z=1:Wk, z=2+b:freq[b]
// (freq blocks also emit row-major bf16 fB).
// ---------------------------------------------------------------------------
__global__ __launch_bounds__(256) void transpose_to_bf16(
    const float* Wq, const float* Wk, const float* freq,
    __hip_bfloat16* WqT, __hip_bfloat16* WkT, __hip_bfloat16* fT, __hip_bfloat16* fB) {
  int z = blockIdx.z;
  const float* src; __hip_bfloat16* dst; __hip_bfloat16* cpy = nullptr; int R, C;
  if (z == 0)      { src = Wq; dst = WqT; R = 1024; C = 1024; }
  else if (z == 1) { src = Wk; dst = WkT; R = 1024; C = 1024; }
  else {
    int b = z - 2;
    src = freq + (size_t)b*2048*1024; dst = fT + (size_t)b*1024*2048;
    cpy = fB + (size_t)b*2048*1024; R = 2048; C = 1024;
  }
  int r0 = blockIdx.x * 32, c0 = blockIdx.y * 32;
  if (r0 >= R) return;
  __shared__ float tile[32][33];
  int tx = threadIdx.x, ty = threadIdx.y;   // 32 x 8
#pragma unroll
  for (int i = 0; i < 4; ++i) {
    float v = src[(size_t)(r0 + ty + i*8) * C + c0 + tx];
    tile[ty + i*8][tx] = v;
    if (cpy) cpy[(size_t)(r0 + ty + i*8) * C + c0 + tx] = __float2bfloat16(v);
  }
  __syncthreads();
#pragma unroll
  for (int i = 0; i < 4; ++i)
    dst[(size_t)(c0 + ty + i*8) * R + r0 + tx] = __float2bfloat16(tile[tx][ty + i*8]);
}

// ---------------------------------------------------------------------------
// 256x256 8-phase GEMM, C = A * B^T.
// MODE 0: z=0: Q=rB*WqT^T  z=1: K=fB*WkT^T  -> bf16 packed into d_out.
// MODE 1: S = Q*K^T per batch (z) from d_out-packed Q,K -> bf16 S.
// MODE 2: O = P*fT^T per batch -> f32 0.5*v into out[:,1024+col].
//
// LDS map (131072 B): buf d in [d*65536, +65536): A-half h at +h*16384,
// B-half h at +32768+h*16384. Each half = 16 subtiles of 1KiB ([16r][32c] bf16,
// XOR-swizzled: inner_byte ^= ((row&8)<<2)). Tile t lives in buf[t&1].
// Wave w stages rows [h*128 + w*16, +16) of each half (2 gload_lds, q=0/1
// covering col groups 0/1); global source is inverse-swizzled per lane.
// ---------------------------------------------------------------------------
template<int MODE>
__global__ __launch_bounds__(512, 2) void gemm256(
    const void* pA0, const void* pA1, const void* pB0, const void* pB1, void* pC) {
  constexpr int NX = (MODE == 0) ? 64 : 8;
  constexpr int NY = (MODE == 1) ? 8 : 4;
  constexpr int NZ = (MODE == 0) ? 2 : 8;
  constexpr int NT = (MODE == 2) ? 32 : 16;            // K / 64
  constexpr long LDA = (MODE == 0) ? 1024 : (MODE == 1) ? 4096 : 2048;
  constexpr long LDB = (MODE == 0) ? 1024 : (MODE == 1) ? 4096 : 2048;
  constexpr int NWG = NX * NY * NZ;                    // 512 / 512 / 256, %8==0

  // T1: bijective XCD swizzle (nwg % 8 == 0)
  int bid = blockIdx.x;
  int wg = (bid & 7) * (NWG >> 3) + (bid >> 3);
  int bx = wg % NX, by = (wg / NX) % NY, bz = wg / (NX * NY);
  const int row0 = bx * 256, col0 = by * 256;

  const int tid = threadIdx.x;
  const int wid = tid >> 6, l = tid & 63;
  const int wr = wid >> 2, wc = wid & 3;               // 2 x 4 wave grid
  const int lm = l & 15, lk = (l >> 4) & 3;

  const __hip_bfloat16 *A, *B;
  if constexpr (MODE == 0) {
    A = (const __hip_bfloat16*)(bz ? pA1 : pA0);
    B = (const __hip_bfloat16*)(bz ? pB1 : pB0);
  } else if constexpr (MODE == 1) {
    A = (const __hip_bfloat16*)pA0 + (size_t)bz*2048*4096 + 2048;  // Q
    B = (const __hip_bfloat16*)pA0 + (size_t)bz*2048*4096;         // K
  } else {
    A = (const __hip_bfloat16*)pA0 + (size_t)bz*2048*2048;         // P
    B = (const __hip_bfloat16*)pB0 + (size_t)bz*1024*2048;         // freqT
  }

  __shared__ __align__(16) unsigned char lds[131072];

  // staging: lane l -> subtile inner row (l>>2), inverse-swizzled col
  const int srow = l >> 2;
  const int scol = ((l & 3) * 8) ^ ((l & 32) ? 16 : 0);
  const __hip_bfloat16* sA = A + (size_t)(row0 + wid*16 + srow) * LDA + scol;
  const __hip_bfloat16* sB = B + (size_t)(col0 + wid*16 + srow) * LDB + scol;

#define STAGE(mat, h, t) { \
    const __hip_bfloat16* _s = ((mat) ? sB : sA) \
        + (size_t)(h)*128*((mat) ? LDB : LDA) + (size_t)(t)*64; \
    unsigned _d = (unsigned)(((t)&1)*65536 + (mat)*32768 + (h)*16384 + wid*2048); \
    GLOAD_LDS16(_s,      lds + _d); \
    GLOAD_LDS16(_s + 32, lds + _d + 1024); }

  // ds_read: swizzled inner offset (same involution as the staged source)
  const int rdo = ((lm * 64) + (lk * 16)) ^ ((lm & 8) << 2);

  bf16x8 af[4][2];   // A quadrant frags (4 mi x 2 k-halves)
  bf16x8 bfr[4][2];  // all B frags for current tile
  f32x4 acc[8][4];
#pragma unroll
  for (int m = 0; m < 8; ++m)
#pragma unroll
    for (int n = 0; n < 4; ++n) acc[m][n] = (f32x4){0.f, 0.f, 0.f, 0.f};

#define LOAD_A(cur, qm) \
  _Pragma("unroll") for (int mi = 0; mi < 4; ++mi) \
  _Pragma("unroll") for (int s = 0; s < 2; ++s) \
    af[mi][s] = *(const bf16x8*)(lds + (cur)*65536 + wr*16384 \
                 + (((qm)*4 + mi)*2 + s)*1024 + rdo);
#define LOAD_B(cur, nlo) \
  _Pragma("unroll") for (int ni = 0; ni < 2; ++ni) \
  _Pragma("unroll") for (int s = 0; s < 2; ++s) \
    bfr[(nlo)+ni][s] = *(const bf16x8*)(lds + (cur)*65536 + 32768 + (wc>>1)*16384 \
                 + ((((wc&1)*4 + (nlo) + ni)*2) + s)*1024 + rdo);
#define MFMA_Q(qm, qn) \
  __builtin_amdgcn_s_setprio(1); \
  _Pragma("unroll") for (int mi = 0; mi < 4; ++mi) \
  _Pragma("unroll") for (int ni = 0; ni < 2; ++ni) \
  _Pragma("unroll") for (int s = 0; s < 2; ++s) \
    acc[(qm)*4 + mi][(qn)*2 + ni] = __builtin_amdgcn_mfma_f32_16x16x32_bf16( \
        af[mi][s], bfr[(qn)*2 + ni][s], acc[(qm)*4 + mi][(qn)*2 + ni], 0, 0, 0); \
  __builtin_amdgcn_s_setprio(0);
#define BARR __builtin_amdgcn_s_barrier();
#define LGKM0 asm volatile("s_waitcnt lgkmcnt(0)" ::: "memory");
#define VMW2 asm volatile("s_waitcnt vmcnt(2)" ::: "memory");

  // prologue: tile0 (4 halves) + A0(tile1); wait tile0 (10 outstanding -> <=2)
  STAGE(0, 0, 0) STAGE(0, 1, 0) STAGE(1, 0, 0) STAGE(1, 1, 0)
  STAGE(0, 0, 1)
  VMW2 BARR

  for (int g = 0; g < NT; ++g) {
    const int cur = g & 1;
    const int t1 = (g + 1 < NT) ? g + 1 : NT - 1;   // clamped re-stage is
    const int t2 = (g + 2 < NT) ? g + 2 : NT - 1;   // value-identical (benign)
    // P1
    LOAD_A(cur, 0) LOAD_B(cur, 0) STAGE(0, 1, t1)
    BARR LGKM0 MFMA_Q(0, 0) BARR
    // P2
    LOAD_B(cur, 2) STAGE(1, 0, t1)
    BARR LGKM0 MFMA_Q(0, 1) BARR
    // P3
    LOAD_A(cur, 1) STAGE(1, 1, t1)
    BARR LGKM0 MFMA_Q(1, 0) BARR
    // P4 (A0 of t2 goes into buf[g&1]: safe, last ds_read of it was P3)
    STAGE(0, 0, t2)
    BARR MFMA_Q(1, 1) VMW2 BARR
  }

  // ---- epilogue ----
#pragma unroll
  for (int m = 0; m < 8; ++m)
#pragma unroll
    for (int n = 0; n < 4; ++n)
#pragma unroll
      for (int r = 0; r < 4; ++r) {
        float v = acc[m][n][r];
        int grow = row0 + wr*128 + m*16 + lk*4 + r;
        int gcol = col0 + wc*64 + n*16 + lm;
        if constexpr (MODE == 0) {
          __hip_bfloat16* Cb = (__hip_bfloat16*)pC;
          Cb[(size_t)grow * 4096 + (bz ? 0 : 2048) + gcol] = __float2bfloat16(v);
        } else if constexpr (MODE == 1) {
          __hip_bfloat16* Cb = (__hip_bfloat16*)pC + (size_t)bz*2048*2048;
          Cb[(size_t)grow * 2048 + gcol] = __float2bfloat16(v);
        } else {
          float* Cf = (float*)pC;
          Cf[((size_t)(bz*2048 + grow)) * 2048 + 1024 + gcol] = 0.5f * v;
        }
      }
#undef STAGE
#undef LOAD_A
#undef LOAD_B
#undef MFMA_Q
#undef BARR
#undef LGKM0
#undef VMW2
}

// ---------------------------------------------------------------------------
// Row softmax in place over S (bf16, 2048 per row), scale 1/32 folded in.
// ---------------------------------------------------------------------------
__global__ __launch_bounds__(256) void softmax_rows(__hip_bfloat16* S) {
  const int row = blockIdx.x;
  const int t = threadIdx.x;
  uint32_t* p32 = (uint32_t*)(S + (size_t)row * 2048);
  uint4 raw = ((const uint4*)p32)[t];
  uint32_t w[4] = {raw.x, raw.y, raw.z, raw.w};
  float x[8];
#pragma unroll
  for (int i = 0; i < 4; ++i) {
    x[2*i]   = b2f((unsigned short)(w[i] & 0xffffu)) * 0.03125f;
    x[2*i+1] = b2f((unsigned short)(w[i] >> 16))     * 0.03125f;
  }
  float mx = x[0];
#pragma unroll
  for (int i = 1; i < 8; ++i) mx = fmaxf(mx, x[i]);
  for (int o = 32; o; o >>= 1) mx = fmaxf(mx, __shfl_xor(mx, o));
  __shared__ float redm[4], reds[4];
  int wid = t >> 6;
  if ((t & 63) == 0) redm[wid] = mx;
  __syncthreads();
  mx = fmaxf(fmaxf(redm[0], redm[1]), fmaxf(redm[2], redm[3]));
  float e[8], s = 0.f;
#pragma unroll
  for (int i = 0; i < 8; ++i) { e[i] = __expf(x[i] - mx); s += e[i]; }
  for (int o = 32; o; o >>= 1) s += __shfl_xor(s, o);
  if ((t & 63) == 0) reds[wid] = s;
  __syncthreads();
  s = reds[0] + reds[1] + reds[2] + reds[3];
  float inv = 1.0f / s;
  uint32_t o[4];
#pragma unroll
  for (int i = 0; i < 4; ++i)
    o[i] = (uint32_t)f2b(e[2*i] * inv) | ((uint32_t)f2b(e[2*i+1] * inv) << 16);
  ((uint4*)p32)[t] = make_uint4(o[0], o[1], o[2], o[3]);
}

// ---------------------------------------------------------------------------
// out[m][0:1024] = rgb[m][:]
// ---------------------------------------------------------------------------
__global__ __launch_bounds__(256) void copy_rgb_kernel(const float* rgb, float* out) {
  size_t i = (size_t)blockIdx.x * 256 + threadIdx.x;
  size_t m = i >> 8;
  int c = (int)(i & 255) << 2;
  f32x4 v = *(const f32x4*)(rgb + m * 1024 + c);
  *(f32x4*)(out + m * 2048 + c) = v;
}

// ---------------------------------------------------------------------------
extern "C" void kernel_launch(void* const* d_in, const int* in_sizes, int n_in,
                              void* d_out, int out_size, void* d_ws, size_t ws_size,
                              hipStream_t stream) {
  const float* rgb  = (const float*)d_in[0];
  const float* freq = (const float*)d_in[1];
  // d_in[2] = ifreq (dead), d_in[5] = Wv (dead)
  const float* Wq   = (const float*)d_in[3];
  const float* Wk   = (const float*)d_in[4];
  float* out = (float*)d_out;

  const size_t WS_NEED = (size_t)100 * 1024 * 1024;
  if (ws_size < WS_NEED) return;

  char* ws = (char*)d_ws;
  __hip_bfloat16* rB  = (__hip_bfloat16*)(ws);
  __hip_bfloat16* fB  = (__hip_bfloat16*)(ws + ((size_t)32 << 20));
  __hip_bfloat16* S   = (__hip_bfloat16*)(ws);                       // overlays rB/fB
  __hip_bfloat16* fT  = (__hip_bfloat16*)(ws + ((size_t)64 << 20));
  __hip_bfloat16* WqT = (__hip_bfloat16*)(ws + ((size_t)96 << 20));
  __hip_bfloat16* WkT = (__hip_bfloat16*)(ws + ((size_t)98 << 20));

  hipLaunchKernelGGL(cast_rgb_bf16, dim3(8192), dim3(256), 0, stream, rgb, rB);
  hipLaunchKernelGGL(transpose_to_bf16, dim3(64, 32, 10), dim3(32, 8), 0, stream,
                     Wq, Wk, freq, WqT, WkT, fT, fB);
  hipLaunchKernelGGL((gemm256<0>), dim3(512), dim3(512), 0, stream,
                     (const void*)rB, (const void*)fB, (const void*)WqT, (const void*)WkT, (void*)out);
  hipLaunchKernelGGL((gemm256<1>), dim3(512), dim3(512), 0, stream,
                     (const void*)out, nullptr, nullptr, nullptr, (void*)S);
  hipLaunchKernelGGL(softmax_rows, dim3(16384), dim3(256), 0, stream, S);
  hipLaunchKernelGGL((gemm256<2>), dim3(256), dim3(512), 0, stream,
                     (const void*)S, nullptr, (const void*)fT, nullptr, (void*)out);
  hipLaunchKernelGGL(copy_rgb_kernel, dim3(16384), dim3(256), 0, stream, rgb, out);
}